// Round 1
// baseline (603.017 us; speedup 1.0000x reference)
//
#include <hip/hip_runtime.h>

#define EPS 1e-5f
#define K3_NCH 16

// ---------------- K0: fold BN into weights, transpose for s_load ----------------
// W1wT[cin][co]  = comp_w[co][cin] * bn1s[co]                     (256 x 64)
// b1f[co]        = (comp_b - bn1_m)*bn1s + bn1_b
// encT[p][cin][dy*3+dx][k pad32] = enc_w[4k+p][cin][dy][dx]*bn2s[4k+p]
// biasT[p][k pad32] = (enc_b - bn2_m)*bn2s + bn2_b  at channel 4k+p
__global__ void k0_prep(const float* __restrict__ comp_w, const float* __restrict__ comp_b,
                        const float* __restrict__ bn1_g, const float* __restrict__ bn1_b,
                        const float* __restrict__ bn1_m, const float* __restrict__ bn1_v,
                        const float* __restrict__ enc_w, const float* __restrict__ enc_b,
                        const float* __restrict__ bn2_g, const float* __restrict__ bn2_b,
                        const float* __restrict__ bn2_m, const float* __restrict__ bn2_v,
                        float* __restrict__ W1wT, float* __restrict__ b1f,
                        float* __restrict__ encT, float* __restrict__ biasT)
{
    int tid = threadIdx.x; // 256 threads, 1 block
    for (int i = tid; i < 256 * 64; i += 256) {
        int cin = i >> 6, co = i & 63;
        float s = bn1_g[co] * rsqrtf(bn1_v[co] + EPS);
        W1wT[i] = comp_w[co * 256 + cin] * s;
    }
    if (tid < 64) {
        float s = bn1_g[tid] * rsqrtf(bn1_v[tid] + EPS);
        b1f[tid] = (comp_b[tid] - bn1_m[tid]) * s + bn1_b[tid];
    }
    for (int i = tid; i < 4 * 64 * 9 * 32; i += 256) {
        int k = i & 31;
        int rest = i >> 5;          // (p*64+cin)*9 + dxy
        int dxy = rest % 9;
        int tmp = rest / 9;         // p*64+cin
        int cin = tmp & 63, p = tmp >> 6;
        float v = 0.f;
        if (k < 25) {
            int ko = 4 * k + p;
            float s = bn2_g[ko] * rsqrtf(bn2_v[ko] + EPS);
            v = enc_w[(ko * 64 + cin) * 9 + dxy] * s;
        }
        encT[i] = v;
    }
    if (tid < 4 * 32) {
        int p = tid >> 5, k = tid & 31;
        float v = 0.f;
        if (k < 25) {
            int ko = 4 * k + p;
            float s = bn2_g[ko] * rsqrtf(bn2_v[ko] + EPS);
            v = (enc_b[ko] - bn2_m[ko]) * s + bn2_b[ko];
        }
        biasT[tid] = v;
    }
}

// ---------------- K1: conv1x1 + bias + ReLU ----------------
// grid 256 = b(8) * posTile(16) * coHalf(2); 256 thr; thread: 1 pos, 32 co accumulators
__global__ __launch_bounds__(256) void k1_conv1(const float* __restrict__ X,
                                                const float* __restrict__ W1wT,
                                                const float* __restrict__ b1f,
                                                float* __restrict__ W1)
{
    int blk = blockIdx.x;
    int coh = blk & 1;
    int pt  = (blk >> 1) & 15;
    int b   = blk >> 5;
    int pos = pt * 256 + threadIdx.x;
    const float* xp = X + (size_t)b * 256 * 4096 + pos;
    const float* wp = W1wT + coh * 32;      // uniform -> s_load
    float acc[32];
#pragma unroll
    for (int k = 0; k < 32; ++k) acc[k] = 0.f;
#pragma unroll 8
    for (int cin = 0; cin < 256; ++cin) {
        float x = xp[(size_t)cin * 4096];
        const float* w = wp + cin * 64;
#pragma unroll
        for (int k = 0; k < 32; ++k) acc[k] = fmaf(w[k], x, acc[k]);
    }
    float* op = W1 + ((size_t)b * 64 + coh * 32) * 4096 + pos;
#pragma unroll
    for (int k = 0; k < 32; ++k) {
        float v = acc[k] + b1f[coh * 32 + k];
        op[(size_t)k * 4096] = fmaxf(v, 0.f);
    }
}

// ---------------- K2: conv3x3 + BN + pixel-shuffle + softmax(25) ----------------
// grid 512 = b(8) * coarseTile(8x8); 256 thr; wave index = sub-position p (wave-uniform
// weight reads -> s_load); each thread: one coarse pixel, 25 channels, own softmax.
__global__ __launch_bounds__(256) void k2_conv2(const float* __restrict__ W1,
                                                const float* __restrict__ encT,
                                                const float* __restrict__ biasT,
                                                float* __restrict__ Wsm)
{
    __shared__ float tile[64 * 10 * 10];    // 25.6 KB, zero-padded halo
    int blk = blockIdx.x;
    int tc = blk & 7;
    int tr = (blk >> 3) & 7;
    int b  = blk >> 6;
    int tid = threadIdx.x;

    const float* wb = W1 + (size_t)b * 64 * 4096;
    for (int i = tid; i < 6400; i += 256) {
        int cin = i / 100;
        int rr = (i - cin * 100) / 10;
        int cc = i - cin * 100 - rr * 10;
        int r = tr * 8 - 1 + rr, c = tc * 8 - 1 + cc;
        float v = 0.f;
        if (r >= 0 && r < 64 && c >= 0 && c < 64) v = wb[cin * 4096 + r * 64 + c];
        tile[i] = v;
    }
    __syncthreads();

    int p = __builtin_amdgcn_readfirstlane(tid >> 6);   // sub-position, wave-uniform
    int lane = tid & 63;
    int pr = lane >> 3, pc = lane & 7;
    const float* wt = encT + p * 64 * 9 * 32;           // scalar base
    float acc[25];
#pragma unroll
    for (int k = 0; k < 25; ++k) acc[k] = 0.f;

    for (int cin = 0; cin < 64; ++cin) {
#pragma unroll
        for (int dy = 0; dy < 3; ++dy) {
#pragma unroll
            for (int dx = 0; dx < 3; ++dx) {
                float v = tile[cin * 100 + (pr + dy) * 10 + (pc + dx)];
                const float* w = wt + (cin * 9 + dy * 3 + dx) * 32; // uniform -> s_load
#pragma unroll
                for (int k = 0; k < 25; ++k) acc[k] = fmaf(w[k], v, acc[k]);
            }
        }
    }

    const float* bp = biasT + p * 32;
    float mx = -1e30f;
#pragma unroll
    for (int k = 0; k < 25; ++k) { acc[k] += bp[k]; mx = fmaxf(mx, acc[k]); }
    float sum = 0.f;
#pragma unroll
    for (int k = 0; k < 25; ++k) { acc[k] = __expf(acc[k] - mx); sum += acc[k]; }
    float rs = 1.f / sum;
#pragma unroll
    for (int k = 0; k < 25; ++k) acc[k] *= rs;

    int py = p >> 1, px = p & 1;
    int y = (tr * 8 + pr) * 2 + py, x = (tc * 8 + pc) * 2 + px;
    float* op = Wsm + (((size_t)b * 128 + y) * 128 + x) * 28;   // 112B-aligned
#pragma unroll
    for (int k = 0; k < 6; ++k) {
        float4 v = make_float4(acc[k * 4], acc[k * 4 + 1], acc[k * 4 + 2], acc[k * 4 + 3]);
        *(float4*)(op + k * 4) = v;
    }
    op[24] = acc[24];
}

// ---------------- K3: bilinear parity planes + 5x5 weighted reassembly ----------------
// grid 8192 = b(8) * tile(8x8 coarse => 16x16 out) * chunk(16 ch of 16), chunk fastest.
// tid = csub(2b)|p(2b)|trow(3b)|half(1b). Thread: 4 x-outputs (one parity) x 4 channels,
// 100 softmax weights in regs. LDS bounce fixes store coalescing.
__global__ __launch_bounds__(256, 3) void k3_carafe(const float* __restrict__ X,
                                                    const float* __restrict__ Wsm,
                                                    float* __restrict__ out)
{
    __shared__ float P[4 * K3_NCH * 144];   // parity planes [p][c][12][12]  36.9 KB
    __shared__ float Bx[4096];              // X tile (3136 used) then bounce, 16 KB

    int blk = blockIdx.x;
    int chunk = blk & 15;
    int tile  = (blk >> 4) & 63;
    int b     = blk >> 10;
    int G0 = (tile >> 3) * 8;
    int H0 = (tile & 7) * 8;
    int c0 = chunk * K3_NCH;
    int tid = threadIdx.x;

    // phase 1: X tile [c][14][14], index-clamped (== jax resize edge renorm)
    {
        const float* xb = X + (size_t)(b * 256 + c0) * 4096;
        for (int i = tid; i < K3_NCH * 196; i += 256) {
            int c = i / 196;
            int r = (i - c * 196) / 14;
            int s = i - c * 196 - r * 14;
            int gr = G0 - 3 + r; gr = gr < 0 ? 0 : (gr > 63 ? 63 : gr);
            int gc = H0 - 3 + s; gc = gc < 0 ? 0 : (gc > 63 ? 63 : gc);
            Bx[i] = xb[(size_t)c * 4096 + gr * 64 + gc];
        }
    }
    __syncthreads();

    // phase 2: 4 parity planes, zero outside [0,64) (CARAFE zero-pad)
    for (int i = tid; i < 4 * K3_NCH * 144; i += 256) {
        int s = i % 12;
        int t = (i / 12) % 12;
        int c = (i / 144) % K3_NCH;
        int p = i / (144 * K3_NCH);
        int py = p >> 1, px = p & 1;
        int tg = G0 - 2 + t, sg = H0 - 2 + s;
        float v = 0.f;
        if (tg >= 0 && tg < 64 && sg >= 0 && sg < 64) {
            int r0 = tg - 1 + py, r1 = r0 + 1;
            float wy0 = py ? 0.75f : 0.25f, wy1 = 1.f - wy0;
            int q0 = sg - 1 + px, q1 = q0 + 1;
            float wx0 = px ? 0.75f : 0.25f, wx1 = 1.f - wx0;
            r0 = r0 < 0 ? 0 : (r0 > 63 ? 63 : r0);  r0 -= (G0 - 3);
            r1 = r1 < 0 ? 0 : (r1 > 63 ? 63 : r1);  r1 -= (G0 - 3);
            q0 = q0 < 0 ? 0 : (q0 > 63 ? 63 : q0);  q0 -= (H0 - 3);
            q1 = q1 < 0 ? 0 : (q1 > 63 ? 63 : q1);  q1 -= (H0 - 3);
            const float* xc = Bx + c * 196;
            float v00 = xc[r0 * 14 + q0], v01 = xc[r0 * 14 + q1];
            float v10 = xc[r1 * 14 + q0], v11 = xc[r1 * 14 + q1];
            v = wy0 * (wx0 * v00 + wx1 * v01) + wy1 * (wx0 * v10 + wx1 * v11);
        }
        P[i] = v;
    }
    __syncthreads();

    // phase 3
    int csub = tid >> 6;
    int p    = (tid >> 4) & 3;
    int trow = (tid >> 1) & 7;
    int half = tid & 1;
    int py = p >> 1, px = p & 1;
    int y  = (G0 + trow) * 2 + py;
    int x0 = (H0 + half * 4) * 2 + px;

    float w[4][25];
    {
        const float* wp = Wsm + (((size_t)b * 128 + y) * 128 + x0) * 28;
#pragma unroll
        for (int d = 0; d < 4; ++d) {
            const float* q = wp + d * 56;   // x stride 2 -> 2*28 floats
#pragma unroll
            for (int k = 0; k < 6; ++k) {
                float4 t = *(const float4*)(q + k * 4);
                w[d][k * 4 + 0] = t.x; w[d][k * 4 + 1] = t.y;
                w[d][k * 4 + 2] = t.z; w[d][k * 4 + 3] = t.w;
            }
            w[d][24] = q[24];
        }
    }

    float accs[4][4];
    const float* pbase = P + (p * K3_NCH + csub * 4) * 144 + trow * 12 + half * 4;
#pragma unroll
    for (int cc = 0; cc < 4; ++cc) {
        const float* pc = pbase + cc * 144;
        float a0 = 0.f, a1 = 0.f, a2 = 0.f, a3 = 0.f;
#pragma unroll
        for (int i5 = 0; i5 < 5; ++i5) {
            const float* row = pc + i5 * 12;    // 16B aligned
            float4 ra = *(const float4*)(row);
            float4 rb = *(const float4*)(row + 4);
            float r[8];
            r[0] = ra.x; r[1] = ra.y; r[2] = ra.z; r[3] = ra.w;
            r[4] = rb.x; r[5] = rb.y; r[6] = rb.z; r[7] = rb.w;
#pragma unroll
            for (int j = 0; j < 5; ++j) {
                a0 = fmaf(w[0][i5 * 5 + j], r[j],     a0);
                a1 = fmaf(w[1][i5 * 5 + j], r[j + 1], a1);
                a2 = fmaf(w[2][i5 * 5 + j], r[j + 2], a2);
                a3 = fmaf(w[3][i5 * 5 + j], r[j + 3], a3);
            }
        }
        accs[cc][0] = a0; accs[cc][1] = a1; accs[cc][2] = a2; accs[cc][3] = a3;
    }

    // bounce: parity-strided accumulators -> dense [c][y][x] 16x16x16
#pragma unroll
    for (int cc = 0; cc < 4; ++cc) {
        int c = csub * 4 + cc;
        int yy = trow * 2 + py;
#pragma unroll
        for (int d = 0; d < 4; ++d) {
            int xx = (half * 4 + d) * 2 + px;
            Bx[c * 256 + yy * 16 + xx] = accs[cc][d];
        }
    }
    __syncthreads();

    // coalesced float4 stores
    int rx = tid & 3;
    int ry = (tid >> 2) & 15;
    int rc = tid >> 6;
#pragma unroll
    for (int i = 0; i < 4; ++i) {
        int c = rc * 4 + i;
        float4 v = *(const float4*)(Bx + c * 256 + ry * 16 + rx * 4);
        float* dst = out + ((size_t)(b * 256 + c0 + c) * 128 + (2 * G0 + ry)) * 128
                         + 2 * H0 + rx * 4;
        *(float4*)dst = v;
    }
}

extern "C" void kernel_launch(void* const* d_in, const int* in_sizes, int n_in,
                              void* d_out, int out_size, void* d_ws, size_t ws_size,
                              hipStream_t stream)
{
    const float* X      = (const float*)d_in[0];
    const float* comp_w = (const float*)d_in[1];
    const float* comp_b = (const float*)d_in[2];
    const float* bn1_g  = (const float*)d_in[3];
    const float* bn1_b  = (const float*)d_in[4];
    const float* bn1_m  = (const float*)d_in[5];
    const float* bn1_v  = (const float*)d_in[6];
    const float* enc_w  = (const float*)d_in[7];
    const float* enc_b  = (const float*)d_in[8];
    const float* bn2_g  = (const float*)d_in[9];
    const float* bn2_b  = (const float*)d_in[10];
    const float* bn2_m  = (const float*)d_in[11];
    const float* bn2_v  = (const float*)d_in[12];

    float* ws   = (float*)d_ws;
    float* W1wT = ws;                 // 16384
    float* b1f  = ws + 16384;         // 64
    float* encT = ws + 16448;         // 73728
    float* biasT= ws + 90176;         // 128
    float* W1   = ws + 90304;         // 2097152 (8 MB)
    float* Wsm  = ws + 2187456;       // 3670016 (14.7 MB); total 23.4 MB

    float* outp = (float*)d_out;

    k0_prep<<<1, 256, 0, stream>>>(comp_w, comp_b, bn1_g, bn1_b, bn1_m, bn1_v,
                                   enc_w, enc_b, bn2_g, bn2_b, bn2_m, bn2_v,
                                   W1wT, b1f, encT, biasT);
    k1_conv1<<<256, 256, 0, stream>>>(X, W1wT, b1f, W1);
    k2_conv2<<<512, 256, 0, stream>>>(W1, encT, biasT, Wsm);
    k3_carafe<<<8192, 256, 0, stream>>>(X, Wsm, outp);
}

// Round 2
// 571.676 us; speedup vs baseline: 1.0548x; 1.0548x over previous
//
#include <hip/hip_runtime.h>

#define EPS 1e-5f

// ---------------- K0: fold BN into weights, transpose for s_load ----------------
__global__ void k0_prep(const float* __restrict__ comp_w, const float* __restrict__ comp_b,
                        const float* __restrict__ bn1_g, const float* __restrict__ bn1_b,
                        const float* __restrict__ bn1_m, const float* __restrict__ bn1_v,
                        const float* __restrict__ enc_w, const float* __restrict__ enc_b,
                        const float* __restrict__ bn2_g, const float* __restrict__ bn2_b,
                        const float* __restrict__ bn2_m, const float* __restrict__ bn2_v,
                        float* __restrict__ W1wT, float* __restrict__ b1f,
                        float* __restrict__ encT, float* __restrict__ biasT)
{
    int tid = threadIdx.x; // 256 threads, 1 block
    for (int i = tid; i < 256 * 64; i += 256) {
        int cin = i >> 6, co = i & 63;
        float s = bn1_g[co] * rsqrtf(bn1_v[co] + EPS);
        W1wT[i] = comp_w[co * 256 + cin] * s;
    }
    if (tid < 64) {
        float s = bn1_g[tid] * rsqrtf(bn1_v[tid] + EPS);
        b1f[tid] = (comp_b[tid] - bn1_m[tid]) * s + bn1_b[tid];
    }
    for (int i = tid; i < 4 * 64 * 9 * 32; i += 256) {
        int k = i & 31;
        int rest = i >> 5;
        int dxy = rest % 9;
        int tmp = rest / 9;
        int cin = tmp & 63, p = tmp >> 6;
        float v = 0.f;
        if (k < 25) {
            int ko = 4 * k + p;
            float s = bn2_g[ko] * rsqrtf(bn2_v[ko] + EPS);
            v = enc_w[(ko * 64 + cin) * 9 + dxy] * s;
        }
        encT[i] = v;
    }
    if (tid < 4 * 32) {
        int p = tid >> 5, k = tid & 31;
        float v = 0.f;
        if (k < 25) {
            int ko = 4 * k + p;
            float s = bn2_g[ko] * rsqrtf(bn2_v[ko] + EPS);
            v = (enc_b[ko] - bn2_m[ko]) * s + bn2_b[ko];
        }
        biasT[tid] = v;
    }
}

// ---------------- K1: conv1x1 + bias + ReLU ----------------
// grid 1024 = cog(8, slowest -> same-XCD for same-X blocks) * b(8) * posTile(16)
// 4 blocks/CU, 16 waves/CU. Thread: 1 pos, 8 co accumulators.
__global__ __launch_bounds__(256, 4) void k1_conv1(const float* __restrict__ X,
                                                   const float* __restrict__ W1wT,
                                                   const float* __restrict__ b1f,
                                                   float* __restrict__ W1)
{
    int blk = blockIdx.x;
    int cog = blk >> 7;            // 0..7; blocks differing only in cog are 128 apart == same XCD
    int rest = blk & 127;
    int b  = rest >> 4;
    int pt = rest & 15;
    int pos = pt * 256 + threadIdx.x;
    const float* xp = X + (size_t)b * 256 * 4096 + pos;
    const float* wp = W1wT + cog * 8;      // uniform -> s_load
    float acc[8];
#pragma unroll
    for (int k = 0; k < 8; ++k) acc[k] = 0.f;
#pragma unroll 8
    for (int cin = 0; cin < 256; ++cin) {
        float x = xp[(size_t)cin * 4096];
        const float* w = wp + cin * 64;
#pragma unroll
        for (int k = 0; k < 8; ++k) acc[k] = fmaf(w[k], x, acc[k]);
    }
    float* op = W1 + ((size_t)b * 64 + cog * 8) * 4096 + pos;
#pragma unroll
    for (int k = 0; k < 8; ++k) {
        float v = acc[k] + b1f[cog * 8 + k];
        op[(size_t)k * 4096] = fmaxf(v, 0.f);
    }
}

// ---------------- K2: conv3x3 + BN + pixel-shuffle + softmax(25) ----------------
__global__ __launch_bounds__(256) void k2_conv2(const float* __restrict__ W1,
                                                const float* __restrict__ encT,
                                                const float* __restrict__ biasT,
                                                float* __restrict__ Wsm)
{
    __shared__ float tile[64 * 10 * 10];
    int blk = blockIdx.x;
    int tc = blk & 7;
    int tr = (blk >> 3) & 7;
    int b  = blk >> 6;
    int tid = threadIdx.x;

    const float* wb = W1 + (size_t)b * 64 * 4096;
    for (int i = tid; i < 6400; i += 256) {
        int cin = i / 100;
        int rr = (i - cin * 100) / 10;
        int cc = i - cin * 100 - rr * 10;
        int r = tr * 8 - 1 + rr, c = tc * 8 - 1 + cc;
        float v = 0.f;
        if (r >= 0 && r < 64 && c >= 0 && c < 64) v = wb[cin * 4096 + r * 64 + c];
        tile[i] = v;
    }
    __syncthreads();

    int p = __builtin_amdgcn_readfirstlane(tid >> 6);
    int lane = tid & 63;
    int pr = lane >> 3, pc = lane & 7;
    const float* wt = encT + p * 64 * 9 * 32;
    float acc[25];
#pragma unroll
    for (int k = 0; k < 25; ++k) acc[k] = 0.f;

    for (int cin = 0; cin < 64; ++cin) {
#pragma unroll
        for (int dy = 0; dy < 3; ++dy) {
#pragma unroll
            for (int dx = 0; dx < 3; ++dx) {
                float v = tile[cin * 100 + (pr + dy) * 10 + (pc + dx)];
                const float* w = wt + (cin * 9 + dy * 3 + dx) * 32;
#pragma unroll
                for (int k = 0; k < 25; ++k) acc[k] = fmaf(w[k], v, acc[k]);
            }
        }
    }

    const float* bp = biasT + p * 32;
    float mx = -1e30f;
#pragma unroll
    for (int k = 0; k < 25; ++k) { acc[k] += bp[k]; mx = fmaxf(mx, acc[k]); }
    float sum = 0.f;
#pragma unroll
    for (int k = 0; k < 25; ++k) { acc[k] = __expf(acc[k] - mx); sum += acc[k]; }
    float rs = 1.f / sum;
#pragma unroll
    for (int k = 0; k < 25; ++k) acc[k] *= rs;

    int py = p >> 1, px = p & 1;
    int y = (tr * 8 + pr) * 2 + py, x = (tc * 8 + pc) * 2 + px;
    float* op = Wsm + (((size_t)b * 128 + y) * 128 + x) * 28;
#pragma unroll
    for (int k = 0; k < 6; ++k) {
        float4 v = make_float4(acc[k * 4], acc[k * 4 + 1], acc[k * 4 + 2], acc[k * 4 + 3]);
        *(float4*)(op + k * 4) = v;
    }
    op[24] = acc[24];
}

// ---------------- K3: bilinear parity planes + 5x5 weighted reassembly ----------------
// Bx: X tile [c][14 rows][16 cols], c-stride 232 (== 8 mod 32 banks, 16B-aligned)
// P : planes [p][c*144 + t*12 + s], p-stride 2312 (== 8 mod 32 banks); reused as bounce
// Thread: 4 x-outputs (same parity row) x 4 channels; w as 4 separate 25-float arrays
// + launch_bounds(256,2) so the compiler keeps them resident (R1: VGPR=68 -> global re-reads).
#define LOADW(W, q) do { \
    float4 t0 = *(const float4*)(q);      float4 t1 = *(const float4*)((q) + 4);  \
    float4 t2 = *(const float4*)((q) + 8); float4 t3 = *(const float4*)((q) + 12); \
    float4 t4 = *(const float4*)((q) + 16); float4 t5 = *(const float4*)((q) + 20); \
    W[0]=t0.x; W[1]=t0.y; W[2]=t0.z; W[3]=t0.w; \
    W[4]=t1.x; W[5]=t1.y; W[6]=t1.z; W[7]=t1.w; \
    W[8]=t2.x; W[9]=t2.y; W[10]=t2.z; W[11]=t2.w; \
    W[12]=t3.x; W[13]=t3.y; W[14]=t3.z; W[15]=t3.w; \
    W[16]=t4.x; W[17]=t4.y; W[18]=t4.z; W[19]=t4.w; \
    W[20]=t5.x; W[21]=t5.y; W[22]=t5.z; W[23]=t5.w; \
    W[24]=(q)[24]; } while (0)

__global__ __launch_bounds__(256, 2) void k3_carafe(const float* __restrict__ X,
                                                    const float* __restrict__ Wsm,
                                                    float* __restrict__ out)
{
    __shared__ __align__(16) float Bx[16 * 232];   // 14.8 KB
    __shared__ __align__(16) float P[4 * 2312];    // 37.0 KB (also bounce: needs 4096)

    int blk = blockIdx.x;
    int chunk = blk & 15;
    int tile  = (blk >> 4) & 63;
    int b     = blk >> 10;
    int G0 = (tile >> 3) * 8;
    int H0 = (tile & 7) * 8;
    int c0 = chunk * 16;
    int tid = threadIdx.x;

    // phase 1: X tile [c][14][14], clamp folded in (== jax resize edge renorm + interior)
    {
        const float* xb = X + (size_t)(b * 256 + c0) * 4096;
        for (int i = tid; i < 16 * 196; i += 256) {
            int c = i / 196;
            int r = (i - c * 196) / 14;
            int s = i - c * 196 - r * 14;
            int gr = G0 - 3 + r; gr = gr < 0 ? 0 : (gr > 63 ? 63 : gr);
            int gc = H0 - 3 + s; gc = gc < 0 ? 0 : (gc > 63 ? 63 : gc);
            Bx[c * 232 + r * 16 + s] = xb[(size_t)c * 4096 + gr * 64 + gc];
        }
    }
    __syncthreads();

    // phase 2: parity-plane rows. Task = (p, c, t); 768 tasks, 3/thread.
    // Wave-uniform p per iteration (192 | wave boundaries), so px branch has no divergence.
#pragma unroll
    for (int k = 0; k < 3; ++k) {
        int tau = tid + 256 * k;
        int pp  = tau / 192;
        int rem = tau - pp * 192;
        int c   = rem / 12;
        int t   = rem - c * 12;
        int py = pp >> 1, px = pp & 1;
        float wy0 = py ? 0.75f : 0.25f, wy1 = 1.f - wy0;
        float wx0 = px ? 0.75f : 0.25f, wx1 = 1.f - wx0;
        bool row_ok = (unsigned)(G0 - 2 + t) < 64u;
        const float* rp0 = Bx + c * 232 + (t + py) * 16;
        float x0[16], x1[16];
#pragma unroll
        for (int q = 0; q < 4; ++q) {
            float4 a = *(const float4*)(rp0 + q * 4);
            float4 e = *(const float4*)(rp0 + 16 + q * 4);
            x0[q*4+0]=a.x; x0[q*4+1]=a.y; x0[q*4+2]=a.z; x0[q*4+3]=a.w;
            x1[q*4+0]=e.x; x1[q*4+1]=e.y; x1[q*4+2]=e.z; x1[q*4+3]=e.w;
        }
        float v[12];
        if (px == 0) {
#pragma unroll
            for (int s = 0; s < 12; ++s)
                v[s] = wy0 * (wx0 * x0[s] + wx1 * x0[s+1]) + wy1 * (wx0 * x1[s] + wx1 * x1[s+1]);
        } else {
#pragma unroll
            for (int s = 0; s < 12; ++s)
                v[s] = wy0 * (wx0 * x0[s+1] + wx1 * x0[s+2]) + wy1 * (wx0 * x1[s+1] + wx1 * x1[s+2]);
        }
#pragma unroll
        for (int s = 0; s < 12; ++s) {
            bool ok = row_ok && ((unsigned)(H0 - 2 + s) < 64u);
            v[s] = ok ? v[s] : 0.f;
        }
        float* dst = P + pp * 2312 + c * 144 + t * 12;
#pragma unroll
        for (int q = 0; q < 3; ++q)
            *(float4*)(dst + q * 4) = make_float4(v[q*4], v[q*4+1], v[q*4+2], v[q*4+3]);
    }

    // weight loads issued before the barrier (latency absorbed by barrier drain)
    int csub = tid >> 6;
    int p    = (tid >> 4) & 3;
    int trow = (tid >> 1) & 7;
    int half = tid & 1;
    int py = p >> 1, px = p & 1;
    int y  = (G0 + trow) * 2 + py;
    int x0o = (H0 + half * 4) * 2 + px;

    float wA[25], wB[25], wC[25], wD[25];
    {
        const float* wp = Wsm + (((size_t)b * 128 + y) * 128 + x0o) * 28;
        LOADW(wA, wp);
        LOADW(wB, wp + 56);
        LOADW(wC, wp + 112);
        LOADW(wD, wp + 168);
    }
    __syncthreads();

    // phase 3: 4 x-outputs x 4 channels, rows shared across x via r[8]
    float accs[4][4];
    const float* pbase = P + p * 2312 + (csub * 4) * 144 + trow * 12 + half * 4;
#pragma unroll
    for (int cc = 0; cc < 4; ++cc) {
        const float* pc = pbase + cc * 144;
        float a0 = 0.f, a1 = 0.f, a2 = 0.f, a3 = 0.f;
#pragma unroll
        for (int i5 = 0; i5 < 5; ++i5) {
            float4 ra = *(const float4*)(pc + i5 * 12);
            float4 rb = *(const float4*)(pc + i5 * 12 + 4);
            float r[8];
            r[0]=ra.x; r[1]=ra.y; r[2]=ra.z; r[3]=ra.w;
            r[4]=rb.x; r[5]=rb.y; r[6]=rb.z; r[7]=rb.w;
#pragma unroll
            for (int j = 0; j < 5; ++j) {
                a0 = fmaf(wA[i5*5+j], r[j],     a0);
                a1 = fmaf(wB[i5*5+j], r[j + 1], a1);
                a2 = fmaf(wC[i5*5+j], r[j + 2], a2);
                a3 = fmaf(wD[i5*5+j], r[j + 3], a3);
            }
        }
        accs[cc][0] = a0; accs[cc][1] = a1; accs[cc][2] = a2; accs[cc][3] = a3;
    }
    __syncthreads();   // all P reads done before bounce overwrites it

    // bounce into P: dense [c][yy][xx] 16x16x16
#pragma unroll
    for (int cc = 0; cc < 4; ++cc) {
        int c = csub * 4 + cc;
        int yy = trow * 2 + py;
#pragma unroll
        for (int d = 0; d < 4; ++d) {
            int xx = (half * 4 + d) * 2 + px;
            P[c * 256 + yy * 16 + xx] = accs[cc][d];
        }
    }
    __syncthreads();

    // coalesced float4 stores
    int rx = tid & 3;
    int ry = (tid >> 2) & 15;
    int rc = tid >> 6;
#pragma unroll
    for (int i = 0; i < 4; ++i) {
        int c = rc * 4 + i;
        float4 v = *(const float4*)(P + c * 256 + ry * 16 + rx * 4);
        float* dst = out + ((size_t)(b * 256 + c0 + c) * 128 + (2 * G0 + ry)) * 128
                         + 2 * H0 + rx * 4;
        *(float4*)dst = v;
    }
}

extern "C" void kernel_launch(void* const* d_in, const int* in_sizes, int n_in,
                              void* d_out, int out_size, void* d_ws, size_t ws_size,
                              hipStream_t stream)
{
    const float* X      = (const float*)d_in[0];
    const float* comp_w = (const float*)d_in[1];
    const float* comp_b = (const float*)d_in[2];
    const float* bn1_g  = (const float*)d_in[3];
    const float* bn1_b  = (const float*)d_in[4];
    const float* bn1_m  = (const float*)d_in[5];
    const float* bn1_v  = (const float*)d_in[6];
    const float* enc_w  = (const float*)d_in[7];
    const float* enc_b  = (const float*)d_in[8];
    const float* bn2_g  = (const float*)d_in[9];
    const float* bn2_b  = (const float*)d_in[10];
    const float* bn2_m  = (const float*)d_in[11];
    const float* bn2_v  = (const float*)d_in[12];

    float* ws   = (float*)d_ws;
    float* W1wT = ws;                 // 16384
    float* b1f  = ws + 16384;         // 64
    float* encT = ws + 16448;         // 73728
    float* biasT= ws + 90176;         // 128
    float* W1   = ws + 90304;         // 2097152 (8 MB)
    float* Wsm  = ws + 2187456;       // 3670016 (14.7 MB)

    float* outp = (float*)d_out;

    k0_prep<<<1, 256, 0, stream>>>(comp_w, comp_b, bn1_g, bn1_b, bn1_m, bn1_v,
                                   enc_w, enc_b, bn2_g, bn2_b, bn2_m, bn2_v,
                                   W1wT, b1f, encT, biasT);
    k1_conv1<<<1024, 256, 0, stream>>>(X, W1wT, b1f, W1);
    k2_conv2<<<512, 256, 0, stream>>>(W1, encT, biasT, Wsm);
    k3_carafe<<<8192, 256, 0, stream>>>(X, Wsm, outp);
}

// Round 3
// 456.841 us; speedup vs baseline: 1.3200x; 1.2514x over previous
//
#include <hip/hip_runtime.h>

#define EPS 1e-5f

// ---------------- K0: fold BN into weights, transpose for s_load ----------------
__global__ void k0_prep(const float* __restrict__ comp_w, const float* __restrict__ comp_b,
                        const float* __restrict__ bn1_g, const float* __restrict__ bn1_b,
                        const float* __restrict__ bn1_m, const float* __restrict__ bn1_v,
                        const float* __restrict__ enc_w, const float* __restrict__ enc_b,
                        const float* __restrict__ bn2_g, const float* __restrict__ bn2_b,
                        const float* __restrict__ bn2_m, const float* __restrict__ bn2_v,
                        float* __restrict__ W1wT, float* __restrict__ b1f,
                        float* __restrict__ encT, float* __restrict__ biasT)
{
    int tid = threadIdx.x; // 256 threads, 1 block
    for (int i = tid; i < 256 * 64; i += 256) {
        int cin = i >> 6, co = i & 63;
        float s = bn1_g[co] * rsqrtf(bn1_v[co] + EPS);
        W1wT[i] = comp_w[co * 256 + cin] * s;
    }
    if (tid < 64) {
        float s = bn1_g[tid] * rsqrtf(bn1_v[tid] + EPS);
        b1f[tid] = (comp_b[tid] - bn1_m[tid]) * s + bn1_b[tid];
    }
    for (int i = tid; i < 4 * 64 * 9 * 32; i += 256) {
        int k = i & 31;
        int rest = i >> 5;
        int dxy = rest % 9;
        int tmp = rest / 9;
        int cin = tmp & 63, p = tmp >> 6;
        float v = 0.f;
        if (k < 25) {
            int ko = 4 * k + p;
            float s = bn2_g[ko] * rsqrtf(bn2_v[ko] + EPS);
            v = enc_w[(ko * 64 + cin) * 9 + dxy] * s;
        }
        encT[i] = v;
    }
    if (tid < 4 * 32) {
        int p = tid >> 5, k = tid & 31;
        float v = 0.f;
        if (k < 25) {
            int ko = 4 * k + p;
            float s = bn2_g[ko] * rsqrtf(bn2_v[ko] + EPS);
            v = (enc_b[ko] - bn2_m[ko]) * s + bn2_b[ko];
        }
        biasT[tid] = v;
    }
}

// ---------------- K1: conv1x1 + bias + ReLU ----------------
// grid 512 = cog(4, slowest -> same-XCD shares X tile via L2) * b(8) * posTile(16)
// 2 blocks/CU, 8 waves/CU. Thread: 1 pos, 16 co accumulators, cin unroll 8 for MLP.
__global__ __launch_bounds__(256, 2) void k1_conv1(const float* __restrict__ X,
                                                   const float* __restrict__ W1wT,
                                                   const float* __restrict__ b1f,
                                                   float* __restrict__ W1)
{
    int blk = blockIdx.x;
    int cog = blk >> 7;            // 0..3
    int b   = (blk >> 4) & 7;
    int pt  = blk & 15;
    int pos = pt * 256 + threadIdx.x;
    const float* xp = X + (size_t)b * 256 * 4096 + pos;
    const float* wp = W1wT + cog * 16;      // uniform -> s_load
    float acc[16];
#pragma unroll
    for (int k = 0; k < 16; ++k) acc[k] = 0.f;
#pragma unroll 8
    for (int cin = 0; cin < 256; ++cin) {
        float x = xp[(size_t)cin * 4096];
        const float* w = wp + cin * 64;
#pragma unroll
        for (int k = 0; k < 16; ++k) acc[k] = fmaf(w[k], x, acc[k]);
    }
    float* op = W1 + ((size_t)b * 64 + cog * 16) * 4096 + pos;
#pragma unroll
    for (int k = 0; k < 16; ++k) {
        float v = acc[k] + b1f[cog * 16 + k];
        op[(size_t)k * 4096] = fmaxf(v, 0.f);
    }
}

// ---------------- K2: conv3x3 + BN + pixel-shuffle + softmax(25) ----------------
// 512 threads = 8 waves = p(4) x cinHalf(2). Halves the 576-long s_load chain and
// doubles resident waves (R2: 8 waves/CU latency-bound). Partial accs combined in LDS.
__global__ __launch_bounds__(512, 4) void k2_conv2(const float* __restrict__ W1,
                                                   const float* __restrict__ encT,
                                                   const float* __restrict__ biasT,
                                                   float* __restrict__ Wsm)
{
    __shared__ float tile[6400];    // 64 cin x 10 x 10, 25.6 KB
    __shared__ float red[6400];     // [p][lane][25] partials, 25.6 KB (stride 25 -> 2-way)
    int blk = blockIdx.x;
    int tc = blk & 7;
    int tr = (blk >> 3) & 7;
    int b  = blk >> 6;
    int tid = threadIdx.x;

    const float* wb = W1 + (size_t)b * 64 * 4096;
    for (int i = tid; i < 6400; i += 512) {
        int cin = i / 100;
        int rr = (i - cin * 100) / 10;
        int cc = i - cin * 100 - rr * 10;
        int r = tr * 8 - 1 + rr, c = tc * 8 - 1 + cc;
        float v = 0.f;
        if (r >= 0 && r < 64 && c >= 0 && c < 64) v = wb[cin * 4096 + r * 64 + c];
        tile[i] = v;
    }
    __syncthreads();

    int w    = tid >> 6;
    int p    = __builtin_amdgcn_readfirstlane(w & 3);
    int cinh = __builtin_amdgcn_readfirstlane(w >> 2);
    int lane = tid & 63;
    int pr = lane >> 3, pc = lane & 7;
    const float* wt = encT + (size_t)(p * 576 + cinh * 288) * 32;  // [p][cin][dxy][32]
    const float* tp = tile + cinh * 32 * 100;
    float acc[25];
#pragma unroll
    for (int k = 0; k < 25; ++k) acc[k] = 0.f;

    for (int cin = 0; cin < 32; ++cin) {
#pragma unroll
        for (int dy = 0; dy < 3; ++dy) {
#pragma unroll
            for (int dx = 0; dx < 3; ++dx) {
                float v = tp[cin * 100 + (pr + dy) * 10 + (pc + dx)];
                const float* wv = wt + (cin * 9 + dy * 3 + dx) * 32;  // uniform -> s_load
#pragma unroll
                for (int k = 0; k < 25; ++k) acc[k] = fmaf(wv[k], v, acc[k]);
            }
        }
    }

    if (cinh == 0) {
        float* rp = red + (p * 64 + lane) * 25;
#pragma unroll
        for (int k = 0; k < 25; ++k) rp[k] = acc[k];
    }
    __syncthreads();
    if (cinh == 1) {
        const float* rp = red + (p * 64 + lane) * 25;
#pragma unroll
        for (int k = 0; k < 25; ++k) acc[k] += rp[k];

        const float* bp = biasT + p * 32;
        float mx = -1e30f;
#pragma unroll
        for (int k = 0; k < 25; ++k) { acc[k] += bp[k]; mx = fmaxf(mx, acc[k]); }
        float sum = 0.f;
#pragma unroll
        for (int k = 0; k < 25; ++k) { acc[k] = __expf(acc[k] - mx); sum += acc[k]; }
        float rs = 1.f / sum;
#pragma unroll
        for (int k = 0; k < 25; ++k) acc[k] *= rs;

        int py = p >> 1, px = p & 1;
        int y = (tr * 8 + pr) * 2 + py, x = (tc * 8 + pc) * 2 + px;
        float* op = Wsm + (((size_t)b * 128 + y) * 128 + x) * 28;
#pragma unroll
        for (int k = 0; k < 6; ++k) {
            float4 v = make_float4(acc[k*4], acc[k*4+1], acc[k*4+2], acc[k*4+3]);
            *(float4*)(op + k * 4) = v;
        }
        op[24] = acc[24];
    }
}

// ---------------- K3: bilinear parity planes + 5x5 weighted reassembly ----------------
// One output pixel per thread, 16 channels; 25 softmax weights in registers (loaded once).
// Bx c-stride 236 (bank-spread), P p-stride 2312 / c-stride 144 / row-stride 12:
// phase-3 b128 reads at tx&~3 -> 4-lane broadcast, 16 uniq addrs, 2 per bank group (free).
#define LOADW(W, q) do { \
    float4 t0 = *(const float4*)(q);       float4 t1 = *(const float4*)((q) + 4);  \
    float4 t2 = *(const float4*)((q) + 8); float4 t3 = *(const float4*)((q) + 12); \
    float4 t4 = *(const float4*)((q) + 16); float4 t5 = *(const float4*)((q) + 20); \
    W[0]=t0.x; W[1]=t0.y; W[2]=t0.z; W[3]=t0.w; \
    W[4]=t1.x; W[5]=t1.y; W[6]=t1.z; W[7]=t1.w; \
    W[8]=t2.x; W[9]=t2.y; W[10]=t2.z; W[11]=t2.w; \
    W[12]=t3.x; W[13]=t3.y; W[14]=t3.z; W[15]=t3.w; \
    W[16]=t4.x; W[17]=t4.y; W[18]=t4.z; W[19]=t4.w; \
    W[20]=t5.x; W[21]=t5.y; W[22]=t5.z; W[23]=t5.w; \
    W[24]=(q)[24]; } while (0)

__global__ __launch_bounds__(256, 3) void k3_carafe(const float* __restrict__ X,
                                                    const float* __restrict__ Wsm,
                                                    float* __restrict__ out)
{
    __shared__ __align__(16) float Bx[16 * 236];   // 15.1 KB
    __shared__ __align__(16) float P[4 * 2312];    // 37.0 KB

    int blk = blockIdx.x;
    int chunk = blk >> 9;           // slowest: all CUs on same chunk; tile-sharers same XCD
    int b     = (blk >> 6) & 7;
    int tile  = blk & 63;
    int G0 = (tile >> 3) * 8;
    int H0 = (tile & 7) * 8;
    int c0 = chunk * 16;
    int tid = threadIdx.x;

    // phase 1: X tile [c][14][14] in 16-wide rows, clamp folded (== jax resize edges)
    {
        const float* xb = X + (size_t)(b * 256 + c0) * 4096;
        for (int i = tid; i < 16 * 196; i += 256) {
            int c = i / 196;
            int r = (i - c * 196) / 14;
            int s = i - c * 196 - r * 14;
            int gr = G0 - 3 + r; gr = gr < 0 ? 0 : (gr > 63 ? 63 : gr);
            int gc = H0 - 3 + s; gc = gc < 0 ? 0 : (gc > 63 ? 63 : gc);
            Bx[c * 236 + r * 16 + s] = xb[(size_t)c * 4096 + gr * 64 + gc];
        }
    }
    __syncthreads();

    // phase 2: parity-plane rows; lane map c=(tid>>2)&15, tl=tid&3 -> write residues
    // 4(c&1)+3tl cover all 8 bank groups evenly. pp wave-uniform (no divergence).
    {
        int c2 = (tid >> 2) & 15;
        int tl = tid & 3;
        int pp = __builtin_amdgcn_readfirstlane(tid >> 6);
        int py2 = pp >> 1, px2 = pp & 1;
        float wy0 = py2 ? 0.75f : 0.25f, wy1 = 1.f - wy0;
        float wx0 = px2 ? 0.75f : 0.25f, wx1 = 1.f - wx0;
#pragma unroll
        for (int k = 0; k < 3; ++k) {
            int t = tl + 4 * k;
            bool row_ok = (unsigned)(G0 - 2 + t) < 64u;
            const float* rp0 = Bx + c2 * 236 + (t + py2) * 16;
            float x0[16], x1[16];
#pragma unroll
            for (int q = 0; q < 4; ++q) {
                float4 a = *(const float4*)(rp0 + q * 4);
                float4 e = *(const float4*)(rp0 + 16 + q * 4);
                x0[q*4+0]=a.x; x0[q*4+1]=a.y; x0[q*4+2]=a.z; x0[q*4+3]=a.w;
                x1[q*4+0]=e.x; x1[q*4+1]=e.y; x1[q*4+2]=e.z; x1[q*4+3]=e.w;
            }
            float v[12];
            if (px2 == 0) {
#pragma unroll
                for (int s = 0; s < 12; ++s)
                    v[s] = wy0 * (wx0 * x0[s] + wx1 * x0[s+1]) + wy1 * (wx0 * x1[s] + wx1 * x1[s+1]);
            } else {
#pragma unroll
                for (int s = 0; s < 12; ++s)
                    v[s] = wy0 * (wx0 * x0[s+1] + wx1 * x0[s+2]) + wy1 * (wx0 * x1[s+1] + wx1 * x1[s+2]);
            }
#pragma unroll
            for (int s = 0; s < 12; ++s) {
                bool ok = row_ok && ((unsigned)(H0 - 2 + s) < 64u);
                v[s] = ok ? v[s] : 0.f;
            }
            float* dst = P + pp * 2312 + c2 * 144 + t * 12;
#pragma unroll
            for (int q = 0; q < 3; ++q)
                *(float4*)(dst + q * 4) = make_float4(v[q*4], v[q*4+1], v[q*4+2], v[q*4+3]);
        }
    }

    // thread -> output pixel
    int oy = tid >> 4, ox = tid & 15;
    int p3 = (oy & 1) * 2 + (ox & 1);
    int ty = oy >> 1, tx = ox >> 1;
    int y = 2 * G0 + oy, x = 2 * H0 + ox;

    // 25 weights, loaded once (in flight across the barrier drain)
    float w25[25];
    {
        const float* wp = Wsm + (((size_t)b * 128 + y) * 128 + x) * 28;
        LOADW(w25, wp);
    }
    __syncthreads();

    // pre-shift weights by a = tx&3 into an 8-wide zero-padded window (one-time VALU)
    int a = tx & 3;
    float wsh[5][8];
#pragma unroll
    for (int i5 = 0; i5 < 5; ++i5) {
#pragma unroll
        for (int m = 0; m < 8; ++m) {
            float v = 0.f;
            if (m < 5)           v = (a == 0) ? w25[i5*5+m]   : v;
            if (m >= 1 && m < 6) v = (a == 1) ? w25[i5*5+m-1] : v;
            if (m >= 2 && m < 7) v = (a == 2) ? w25[i5*5+m-2] : v;
            if (m >= 3)          v = (a == 3) ? w25[i5*5+m-3] : v;
            wsh[i5][m] = v;
        }
    }

    // phase 3: 16 channels x 5 rows x 8-wide fma; 2 b128 per row, broadcast-aligned
    const float* pc0 = P + p3 * 2312 + ty * 12 + (tx & ~3);
    float* ob = out + ((size_t)(b * 256 + c0) * 128 + y) * 128 + x;
#pragma unroll
    for (int c = 0; c < 16; ++c) {
        const float* pcc = pc0 + c * 144;
        float a0 = 0.f;
#pragma unroll
        for (int i5 = 0; i5 < 5; ++i5) {
            float4 ra = *(const float4*)(pcc + i5 * 12);
            float4 rb = *(const float4*)(pcc + i5 * 12 + 4);
            a0 = fmaf(wsh[i5][0], ra.x, a0);
            a0 = fmaf(wsh[i5][1], ra.y, a0);
            a0 = fmaf(wsh[i5][2], ra.z, a0);
            a0 = fmaf(wsh[i5][3], ra.w, a0);
            a0 = fmaf(wsh[i5][4], rb.x, a0);
            a0 = fmaf(wsh[i5][5], rb.y, a0);
            a0 = fmaf(wsh[i5][6], rb.z, a0);
            a0 = fmaf(wsh[i5][7], rb.w, a0);
        }
        ob[(size_t)c * 16384] = a0;     // 64 consecutive floats/wave = full 64B sectors
    }
}

extern "C" void kernel_launch(void* const* d_in, const int* in_sizes, int n_in,
                              void* d_out, int out_size, void* d_ws, size_t ws_size,
                              hipStream_t stream)
{
    const float* X      = (const float*)d_in[0];
    const float* comp_w = (const float*)d_in[1];
    const float* comp_b = (const float*)d_in[2];
    const float* bn1_g  = (const float*)d_in[3];
    const float* bn1_b  = (const float*)d_in[4];
    const float* bn1_m  = (const float*)d_in[5];
    const float* bn1_v  = (const float*)d_in[6];
    const float* enc_w  = (const float*)d_in[7];
    const float* enc_b  = (const float*)d_in[8];
    const float* bn2_g  = (const float*)d_in[9];
    const float* bn2_b  = (const float*)d_in[10];
    const float* bn2_m  = (const float*)d_in[11];
    const float* bn2_v  = (const float*)d_in[12];

    float* ws   = (float*)d_ws;
    float* W1wT = ws;                 // 16384
    float* b1f  = ws + 16384;         // 64
    float* encT = ws + 16448;         // 73728
    float* biasT= ws + 90176;         // 128
    float* W1   = ws + 90304;         // 2097152 (8 MB)
    float* Wsm  = ws + 2187456;       // 3670016 (14.7 MB)

    float* outp = (float*)d_out;

    k0_prep<<<1, 256, 0, stream>>>(comp_w, comp_b, bn1_g, bn1_b, bn1_m, bn1_v,
                                   enc_w, enc_b, bn2_g, bn2_b, bn2_m, bn2_v,
                                   W1wT, b1f, encT, biasT);
    k1_conv1<<<512, 256, 0, stream>>>(X, W1wT, b1f, W1);
    k2_conv2<<<512, 512, 0, stream>>>(W1, encT, biasT, Wsm);
    k3_carafe<<<8192, 256, 0, stream>>>(X, Wsm, outp);
}